// Round 1
// baseline (749.176 us; speedup 1.0000x reference)
//
#include <hip/hip_runtime.h>
#include <math.h>

#define BB 128
#define EE 64
#define TT 2048
#define F1 16
#define C2 32
#define W1 2049
#define WP 512
#define W3 513
#define CH 33
#define WO 128
#define NCLS 4
#define FEAT 4096

// workspace float offsets
#define OFF_P      ((size_t)0)                    // 128*32*2048 = 8388608
#define OFF_X2     ((size_t)8388608)              // 128*32*2049 = 8392704
#define OFF_STATS  ((size_t)16781312)             // sum[32], sq[32], scale[32], shift[32]
#define OFF_Y      ((size_t)16781440)             // 128*32*512 = 2097152
#define OFF_ZZ     ((size_t)18878592)             // 128*513*32 = 2101248
#define OFF_H      ((size_t)20979840)             // 128*513*33 = 2166912
#define OFF_G      ((size_t)23146752)             // 128*513*33 = 2166912
#define OFF_TNEW   ((size_t)25313664)             // 128
#define OFF_PREP   ((size_t)25313792)             // 16

// ---------------- P[b,c,t] = sum_e w2[c,e] * in[b,e,t] ----------------
__global__ void k_p(const float* __restrict__ in, const float* __restrict__ w2,
                    float* __restrict__ P) {
    int b = blockIdx.y;
    int t0 = blockIdx.x * 128;
    __shared__ float li[64][128];
    __shared__ float lw[32][64];
    const float* ib = in + (size_t)b * EE * TT;
    for (int e = 0; e < 64; e++) li[e][threadIdx.x] = ib[e * TT + t0 + threadIdx.x];
    for (int j = threadIdx.x; j < 2048; j += 128) lw[j >> 6][j & 63] = w2[j];
    __syncthreads();
    float acc[32];
#pragma unroll
    for (int c = 0; c < 32; c++) acc[c] = 0.f;
    for (int e = 0; e < 64; e++) {
        float v = li[e][threadIdx.x];
#pragma unroll
        for (int c = 0; c < 32; c++) acc[c] = fmaf(lw[c][e], v, acc[c]);
    }
    float* Pb = P + (size_t)b * C2 * TT;
    for (int c = 0; c < 32; c++) Pb[c * TT + t0 + threadIdx.x] = acc[c];
}

// ------- x2[b,c,w] = sgn(g1[g]) * sum_k w1[g,k] * P[b,c,w-16+k]; bn2 stats -------
__global__ void k_x2(const float* __restrict__ P, const float* __restrict__ w1,
                     const float* __restrict__ g1, float* __restrict__ x2,
                     float* __restrict__ ssum, float* __restrict__ ssq) {
    int c = blockIdx.y, b = blockIdx.z;
    int w0 = blockIdx.x * 256;
    int g = c >> 1;
    __shared__ float lp[287];
    __shared__ float lw[32];
    __shared__ float red[256];
    const float* Pb = P + ((size_t)b * C2 + c) * TT;
    for (int j = threadIdx.x; j < 287; j += 256) {
        int t = w0 - 16 + j;
        lp[j] = (t >= 0 && t < TT) ? Pb[t] : 0.f;
    }
    if (threadIdx.x < 32) lw[threadIdx.x] = w1[g * 32 + threadIdx.x];
    __syncthreads();
    int w = w0 + threadIdx.x;
    float acc = 0.f;
#pragma unroll
    for (int k = 0; k < 32; k++) acc = fmaf(lw[k], lp[threadIdx.x + k], acc);
    float sgn = (g1[g] < 0.f) ? -1.f : 1.f;
    acc *= sgn;
    bool valid = (w < W1);
    if (valid) x2[((size_t)b * C2 + c) * W1 + w] = acc;
    float v = valid ? acc : 0.f;
    red[threadIdx.x] = v;
    __syncthreads();
    for (int s = 128; s > 0; s >>= 1) {
        if (threadIdx.x < s) red[threadIdx.x] += red[threadIdx.x + s];
        __syncthreads();
    }
    if (threadIdx.x == 0) atomicAdd(&ssum[c], red[0]);
    __syncthreads();
    red[threadIdx.x] = v * v;
    __syncthreads();
    for (int s = 128; s > 0; s >>= 1) {
        if (threadIdx.x < s) red[threadIdx.x] += red[threadIdx.x + s];
        __syncthreads();
    }
    if (threadIdx.x == 0) atomicAdd(&ssq[c], red[0]);
}

__global__ void k_bn2fin(const float* __restrict__ ssum, const float* __restrict__ ssq,
                         const float* __restrict__ gamma, const float* __restrict__ beta,
                         float* __restrict__ scale, float* __restrict__ shift) {
    int c = threadIdx.x;
    if (c >= 32) return;
    float n = (float)(BB * W1);
    float m = ssum[c] / n;
    float var = ssq[c] / n - m * m;
    float sc = gamma[c] * rsqrtf(var + 1e-3f);
    scale[c] = sc;
    shift[c] = beta[c] - m * sc;
}

// ------- y[b,c,wp] = mean_{j<4} elu(scale*x2[...,4wp+j]+shift) -------
__global__ void k_pool(const float* __restrict__ x2, const float* __restrict__ scale,
                       const float* __restrict__ shift, float* __restrict__ y) {
    int idx = blockIdx.x * 256 + threadIdx.x;
    if (idx >= BB * C2 * WP) return;
    int wp = idx & 511;
    int bc = idx >> 9;
    int c = bc & 31;
    const float* xb = x2 + (size_t)bc * W1 + wp * 4;
    float sc = scale[c], sh = shift[c];
    float s = 0.f;
#pragma unroll
    for (int j = 0; j < 4; j++) {
        float v = fmaf(sc, xb[j], sh);
        s += (v > 0.f) ? v : expm1f(v);
    }
    y[idx] = s * 0.25f;
}

// ------- zz[b,w,c] = sum_k ew[c,k]*y[b,c,w-8+k] -------
__global__ void k_ec1(const float* __restrict__ y, const float* __restrict__ ew,
                      float* __restrict__ zz) {
    int b = blockIdx.y;
    int w0 = blockIdx.x * 8;
    int c = threadIdx.x & 31, wl = threadIdx.x >> 5;
    __shared__ float ly[32][25];  // t in [w0-8, w0+14], 23 entries, pad to 25
    __shared__ float lew[32][16];
    const float* yb = y + (size_t)b * C2 * WP;
    for (int j = threadIdx.x; j < 32 * 23; j += 256) {
        int cc = j / 23, tt = j % 23;
        int t = w0 - 8 + tt;
        ly[cc][tt] = (t >= 0 && t < WP) ? yb[cc * WP + t] : 0.f;
    }
    for (int j = threadIdx.x; j < 512; j += 256) lew[j >> 4][j & 15] = ew[j];
    __syncthreads();
    int w = w0 + wl;
    if (w < W3) {
        float acc = 0.f;
#pragma unroll
        for (int k = 0; k < 16; k++) acc = fmaf(lew[c][k], ly[c][wl + k], acc);
        zz[((size_t)b * W3 + w) * C2 + c] = acc;
    }
}

// ------- normalize + add_time + clamp + 33x33 matvec + add_time -> h[b,w,33] -------
__global__ void k_head(const float* __restrict__ zz, const float* __restrict__ lc1,
                       float* __restrict__ h) {
    __shared__ float lw[33 * 33];
    for (int j = threadIdx.x; j < 1089; j += 256) lw[j] = lc1[j];
    __syncthreads();
    int idx = blockIdx.x * 256 + threadIdx.x;
    if (idx >= BB * W3) return;
    const float* zp = zz + (size_t)idx * C2;
    float x[32];
    float ss = 0.f;
#pragma unroll
    for (int i = 0; i < 32; i++) {
        x[i] = zp[i];
        ss += x[i] * x[i];
    }
    float inv = 1.f / (sqrtf(ss) + 1e-8f);
    float s2 = 0.f;
#pragma unroll
    for (int i = 0; i < 32; i++) {
        x[i] *= inv;
        s2 += x[i] * x[i];
    }
    float t = sqrtf(1.f + s2);
    float pre0 = fmaxf(t, 1.f);
    float* hp = h + (size_t)idx * CH;
    float sy = 0.f;
    for (int o = 1; o < 33; o++) {
        const float* wr = lw + o * 33;
        float a = wr[0] * pre0;
#pragma unroll
        for (int i = 0; i < 32; i++) a = fmaf(wr[1 + i], x[i], a);
        hp[o] = a;
        sy += a * a;
    }
    hp[0] = sqrtf(1.f + sy);
}

// ------- fused lorentz_bn + elu + add_time, one block per w -------
__global__ void k_lbn(const float* __restrict__ h, const float* __restrict__ bs,
                      float* __restrict__ g) {
    int w = blockIdx.x;
    int b = threadIdx.x;  // 128
    __shared__ float xs[33][129];
    __shared__ float mu[33];
    __shared__ float red[128];
    __shared__ float varsh, rdenomsh;
    float x[33];
    const float* hp = h + ((size_t)b * W3 + w) * CH;
#pragma unroll
    for (int ch = 0; ch < 33; ch++) {
        x[ch] = hp[ch];
        xs[ch][b] = x[ch];
    }
    __syncthreads();
    if (b < 33) {
        float s = 0.f;
        for (int j = 0; j < 128; j++) s += xs[b][j];
        mu[b] = s * (1.f / 128.f);
    }
    __syncthreads();
    if (b == 0) {
        float a0 = mu[0];
        float sp = 0.f;
        for (int i = 1; i < 33; i++) sp += mu[i] * mu[i];
        rdenomsh = rsqrtf(fmaxf(a0 * a0 - sp, 1e-8f));
    }
    __syncthreads();
    if (b < 33) mu[b] *= rdenomsh;
    __syncthreads();
    float xin = x[0] * mu[0];
#pragma unroll
    for (int i = 1; i < 33; i++) xin -= x[i] * mu[i];
    float dist = acoshf(fmaxf(xin, 1.f + 1e-7f));
    red[b] = dist * dist;
    __syncthreads();
    for (int s = 64; s > 0; s >>= 1) {
        if (b < s) red[b] += red[b + s];
        __syncthreads();
    }
    if (b == 0) varsh = red[0] * (1.f / 128.f);
    __syncthreads();
    float u[33];
#pragma unroll
    for (int ch = 0; ch < 33; ch++) u[ch] = x[ch] - xin * mu[ch];
    float lu = -u[0] * u[0];
#pragma unroll
    for (int i = 1; i < 33; i++) lu += u[i] * u[i];
    float f = dist * rsqrtf(fmaxf(lu, 1e-8f));
    float v[33];
#pragma unroll
    for (int ch = 0; ch < 33; ch++) v[ch] = f * u[ch];
    float corr = -v[0] / (1.f + mu[0]);
    v[0] += corr * (mu[0] + 1.f);
#pragma unroll
    for (int i = 1; i < 33; i++) v[i] += corr * mu[i];
    float sc = bs[w] * rsqrtf(varsh + 1e-5f);
#pragma unroll
    for (int ch = 0; ch < 33; ch++) v[ch] *= sc;
    float nn = -v[0] * v[0];
#pragma unroll
    for (int i = 1; i < 33; i++) nn += v[i] * v[i];
    float n = sqrtf(fmaxf(nn, 1e-9f));
    float shn = sinhf(n) / n;
    float gout0 = 0.f;
    float sg = 0.f;
    float* gp = g + ((size_t)b * W3 + w) * CH;
#pragma unroll
    for (int i = 1; i < 33; i++) {
        float e = shn * v[i];
        e = (e > 0.f) ? e : expm1f(e);
        gp[i] = e;
        sg += e * e;
    }
    gout0 = sqrtf(1.f + sg);
    gp[0] = gout0;
}

// ------- lorentz avgpool + flatten -> feats into d_out (+tnew side buffer) -------
__global__ void k_lpool(const float* __restrict__ g, float* __restrict__ out,
                        float* __restrict__ tnew) {
    int b = blockIdx.x;
    int wp = threadIdx.x;  // 128
    __shared__ float red[128];
    const float* gp = g + ((size_t)b * W3 + wp * 4) * CH;
    float avg[33];
#pragma unroll
    for (int ch = 0; ch < 33; ch++) avg[ch] = 0.f;
    for (int j = 0; j < 4; j++) {
#pragma unroll
        for (int ch = 0; ch < 33; ch++) avg[ch] += gp[j * CH + ch];
    }
#pragma unroll
    for (int ch = 0; ch < 33; ch++) avg[ch] *= 0.25f;
    float sp = 0.f;
#pragma unroll
    for (int i = 1; i < 33; i++) sp += avg[i] * avg[i];
    float l = avg[0] * avg[0] - sp;
    float rd = rsqrtf(fmaxf(l, 1e-8f));
    float q0 = avg[0] * rd;
    float* fb = out + 512 + (size_t)b * 4097;
#pragma unroll
    for (int i = 1; i < 33; i++) fb[1 + wp * 32 + (i - 1)] = avg[i] * rd;
    red[wp] = q0 * q0;
    __syncthreads();
    for (int s = 64; s > 0; s >>= 1) {
        if (wp < s) red[wp] += red[wp + s];
        __syncthreads();
    }
    if (wp == 0) {
        float tn = sqrtf(fmaxf(red[0] - 127.f, 1e-8f));
        fb[0] = tn;
        tnew[b] = tn;
    }
}

__global__ void k_mlrprep(const float* __restrict__ z, const float* __restrict__ a,
                          float* __restrict__ prep) {
    __shared__ float red[256];
    for (int c = 0; c < 4; c++) {
        float s = 0.f;
        for (int j = threadIdx.x; j < FEAT; j += 256) {
            float v = z[c * FEAT + j];
            s = fmaf(v, v, s);
        }
        red[threadIdx.x] = s;
        __syncthreads();
        for (int st = 128; st > 0; st >>= 1) {
            if (threadIdx.x < st) red[threadIdx.x] += red[threadIdx.x + st];
            __syncthreads();
        }
        if (threadIdx.x == 0) {
            float nz = sqrtf(red[0]);
            float ca = coshf(a[c]), sa = sinhf(a[c]);
            float wt = sa * nz;
            float cb = ca * nz;
            float bb = sqrtf(fmaxf(cb * cb - wt * wt, 1e-8f));
            prep[c] = wt;
            prep[4 + c] = bb;
            prep[8 + c] = ca;
        }
        __syncthreads();
    }
}

__global__ void k_mlr(const float* __restrict__ out_feats, const float* __restrict__ tnew,
                      const float* __restrict__ z, const float* __restrict__ prep,
                      float* __restrict__ logits) {
    int b = blockIdx.x;
    __shared__ float red[256];
    const float* fs = out_feats + (size_t)b * 4097 + 1;
    for (int c = 0; c < 4; c++) {
        float s = 0.f;
        for (int j = threadIdx.x; j < FEAT; j += 256) s = fmaf(fs[j], z[c * FEAT + j], s);
        red[threadIdx.x] = s;
        __syncthreads();
        for (int st = 128; st > 0; st >>= 1) {
            if (threadIdx.x < st) red[threadIdx.x] += red[threadIdx.x + st];
            __syncthreads();
        }
        if (threadIdx.x == 0) {
            float alpha = -tnew[b] * prep[c] + prep[8 + c] * red[0];
            float bb = prep[4 + c];
            float d = fabsf(asinhf(alpha / bb));
            float sg = (alpha > 0.f) ? 1.f : ((alpha < 0.f) ? -1.f : 0.f);
            logits[b * 4 + c] = sg * bb * d;
        }
        __syncthreads();
    }
}

extern "C" void kernel_launch(void* const* d_in, const int* in_sizes, int n_in,
                              void* d_out, int out_size, void* d_ws, size_t ws_size,
                              hipStream_t stream) {
    const float* in   = (const float*)d_in[0];
    // d_in[1] = domains (unused by reference)
    const float* w1   = (const float*)d_in[2];   // conv1_w (16,1,1,32)
    const float* g1   = (const float*)d_in[3];   // bn1_gamma (only sign matters)
    // d_in[4] = bn1_beta (provably no effect after bn2)
    const float* w2   = (const float*)d_in[5];   // conv2_w (32,1,64,1)
    const float* g2   = (const float*)d_in[6];
    const float* b2   = (const float*)d_in[7];
    const float* ew   = (const float*)d_in[8];   // ec1_w (32,1,1,16)
    const float* lc1  = (const float*)d_in[9];   // (33,33)
    const float* bs   = (const float*)d_in[10];  // bn_s (513)
    const float* mlra = (const float*)d_in[11];  // (4,)
    const float* mlrz = (const float*)d_in[12];  // (4,4096)
    float* out = (float*)d_out;
    float* ws = (float*)d_ws;

    float* P     = ws + OFF_P;
    float* X2    = ws + OFF_X2;
    float* ssum  = ws + OFF_STATS;
    float* ssq   = ws + OFF_STATS + 32;
    float* scale = ws + OFF_STATS + 64;
    float* shift = ws + OFF_STATS + 96;
    float* Y     = ws + OFF_Y;
    float* ZZ    = ws + OFF_ZZ;
    float* H     = ws + OFF_H;
    float* G     = ws + OFF_G;
    float* TN    = ws + OFF_TNEW;
    float* PREP  = ws + OFF_PREP;

    k_p<<<dim3(16, 128), 128, 0, stream>>>(in, w2, P);
    hipMemsetAsync(ssum, 0, 64 * sizeof(float), stream);
    k_x2<<<dim3(9, 32, 128), 256, 0, stream>>>(P, w1, g1, X2, ssum, ssq);
    k_bn2fin<<<1, 64, 0, stream>>>(ssum, ssq, g2, b2, scale, shift);
    k_pool<<<(BB * C2 * WP) / 256, 256, 0, stream>>>(X2, scale, shift, Y);
    k_ec1<<<dim3(65, 128), 256, 0, stream>>>(Y, ew, ZZ);
    k_head<<<257, 256, 0, stream>>>(ZZ, lc1, H);
    k_lbn<<<513, 128, 0, stream>>>(H, bs, G);
    k_lpool<<<128, 128, 0, stream>>>(G, out, TN);
    k_mlrprep<<<1, 256, 0, stream>>>(mlrz, mlra, PREP);
    k_mlr<<<128, 256, 0, stream>>>(out + 512, TN, mlrz, PREP, out);
}

// Round 2
// 329.260 us; speedup vs baseline: 2.2753x; 2.2753x over previous
//
#include <hip/hip_runtime.h>
#include <math.h>

#define BB 128
#define EE 64
#define TT 2048
#define F1 16
#define C2 32
#define W1 2049
#define WP 512
#define W3 513
#define CH 33
#define NCLS 4
#define FEAT 4096

// workspace float offsets
#define OFF_P      ((size_t)0)                    // 128*32*2048 = 8388608
#define OFF_PSUM   ((size_t)8388608)              // 32*128 = 4096
#define OFF_PSQ    ((size_t)8392704)              // 4096
#define OFF_SS     ((size_t)8396800)              // scale[32], shift[32]
#define OFF_Y      ((size_t)8396864)              // 128*32*512 = 2097152
#define OFF_ZZ     ((size_t)10494016)             // 128*513*32 = 2101248
#define OFF_H      ((size_t)12595264)             // 128*513*33 = 2166912
#define OFF_G      ((size_t)14762176)             // 128*513*33 = 2166912
#define OFF_TNEW   ((size_t)16929088)             // 128
#define OFF_PREP   ((size_t)16929216)             // 16

// ---------------- P[b,c,t] = sum_e w2[c,e] * in[b,e,t] ----------------
__global__ void k_p(const float* __restrict__ in, const float* __restrict__ w2,
                    float* __restrict__ P) {
    int b = blockIdx.y;
    int t0 = blockIdx.x * 128;
    __shared__ float li[64][128];
    __shared__ float lw[32][64];
    const float* ib = in + (size_t)b * EE * TT;
    for (int e = 0; e < 64; e++) li[e][threadIdx.x] = ib[e * TT + t0 + threadIdx.x];
    for (int j = threadIdx.x; j < 2048; j += 128) lw[j >> 6][j & 63] = w2[j];
    __syncthreads();
    float acc[32];
#pragma unroll
    for (int c = 0; c < 32; c++) acc[c] = 0.f;
    for (int e = 0; e < 64; e++) {
        float v = li[e][threadIdx.x];
#pragma unroll
        for (int c = 0; c < 32; c++) acc[c] = fmaf(lw[c][e], v, acc[c]);
    }
    float* Pb = P + (size_t)b * C2 * TT;
    for (int c = 0; c < 32; c++) Pb[c * TT + t0 + threadIdx.x] = acc[c];
}

// ------- bn2 partial stats over x2[b,c,:] (x2 never stored) -------
__global__ void k_stats(const float* __restrict__ P, const float* __restrict__ w1,
                        const float* __restrict__ g1,
                        float* __restrict__ psum, float* __restrict__ psq) {
    int c = blockIdx.x, b = blockIdx.y, g = c >> 1;
    __shared__ float lp[2080];
    __shared__ float lw[32];
    __shared__ float redA[4], redB[4];
    const float* Pb = P + ((size_t)b * C2 + c) * TT;
    for (int j = threadIdx.x; j < 2080; j += 256) {
        int t = j - 16;
        lp[j] = (t >= 0 && t < TT) ? Pb[t] : 0.f;
    }
    if (threadIdx.x < 32) lw[threadIdx.x] = w1[g * 32 + threadIdx.x];
    __syncthreads();
    float ls = 0.f, lq = 0.f;
    for (int chunk = 0; chunk < 9; chunk++) {
        int w = chunk * 256 + threadIdx.x;
        if (w < W1) {
            float acc = 0.f;
#pragma unroll
            for (int k = 0; k < 32; k++) acc = fmaf(lw[k], lp[w + k], acc);
            ls += acc;
            lq = fmaf(acc, acc, lq);
        }
    }
    float sgn = (g1[g] < 0.f) ? -1.f : 1.f;
    ls *= sgn;
#pragma unroll
    for (int d = 1; d < 64; d <<= 1) {
        ls += __shfl_xor(ls, d);
        lq += __shfl_xor(lq, d);
    }
    int wave = threadIdx.x >> 6;
    if ((threadIdx.x & 63) == 0) { redA[wave] = ls; redB[wave] = lq; }
    __syncthreads();
    if (threadIdx.x == 0) {
        psum[c * BB + b] = redA[0] + redA[1] + redA[2] + redA[3];
        psq[c * BB + b]  = redB[0] + redB[1] + redB[2] + redB[3];
    }
}

__global__ void k_bn2fin(const float* __restrict__ psum, const float* __restrict__ psq,
                         const float* __restrict__ gamma, const float* __restrict__ beta,
                         float* __restrict__ ss) {
    int c = threadIdx.x;
    if (c >= 32) return;
    float s = 0.f, q = 0.f;
    for (int b = 0; b < BB; b++) { s += psum[c * BB + b]; q += psq[c * BB + b]; }
    float n = (float)(BB * W1);
    float m = s / n;
    float var = q / n - m * m;
    float sc = gamma[c] * rsqrtf(var + 1e-3f);
    ss[c] = sc;
    ss[32 + c] = beta[c] - m * sc;
}

// ------- recompute conv + bn2 + elu + avgpool4 -> y[b,c,wp] -------
__global__ void k_cpool(const float* __restrict__ P, const float* __restrict__ w1,
                        const float* __restrict__ g1, const float* __restrict__ ss,
                        float* __restrict__ y) {
    int c = blockIdx.x, b = blockIdx.y, g = c >> 1;
    __shared__ float lp[2080];
    __shared__ float lw[32];
    const float* Pb = P + ((size_t)b * C2 + c) * TT;
    for (int j = threadIdx.x; j < 2080; j += 256) {
        int t = j - 16;
        lp[j] = (t >= 0 && t < TT) ? Pb[t] : 0.f;
    }
    if (threadIdx.x < 32) lw[threadIdx.x] = w1[g * 32 + threadIdx.x];
    __syncthreads();
    float sgn = (g1[g] < 0.f) ? -1.f : 1.f;
    float sc = ss[c] * sgn, sh = ss[32 + c];
    float* yb = y + ((size_t)b * C2 + c) * WP;
    for (int wp = threadIdx.x; wp < WP; wp += 256) {
        float win[35];
#pragma unroll
        for (int i = 0; i < 35; i++) win[i] = lp[wp * 4 + i];
        float s = 0.f;
#pragma unroll
        for (int j = 0; j < 4; j++) {
            float acc = 0.f;
#pragma unroll
            for (int k = 0; k < 32; k++) acc = fmaf(lw[k], win[j + k], acc);
            float v = fmaf(sc, acc, sh);
            s += (v > 0.f) ? v : expm1f(v);
        }
        yb[wp] = s * 0.25f;
    }
}

// ------- zz[b,w,c] = sum_k ew[c,k]*y[b,c,w-8+k] -------
__global__ void k_ec1(const float* __restrict__ y, const float* __restrict__ ew,
                      float* __restrict__ zz) {
    int b = blockIdx.y;
    int w0 = blockIdx.x * 8;
    int c = threadIdx.x & 31, wl = threadIdx.x >> 5;
    __shared__ float ly[32][25];
    __shared__ float lew[32][16];
    const float* yb = y + (size_t)b * C2 * WP;
    for (int j = threadIdx.x; j < 32 * 23; j += 256) {
        int cc = j / 23, tt = j % 23;
        int t = w0 - 8 + tt;
        ly[cc][tt] = (t >= 0 && t < WP) ? yb[cc * WP + t] : 0.f;
    }
    for (int j = threadIdx.x; j < 512; j += 256) lew[j >> 4][j & 15] = ew[j];
    __syncthreads();
    int w = w0 + wl;
    if (w < W3) {
        float acc = 0.f;
#pragma unroll
        for (int k = 0; k < 16; k++) acc = fmaf(lew[c][k], ly[c][wl + k], acc);
        zz[((size_t)b * W3 + w) * C2 + c] = acc;
    }
}

// ------- normalize + add_time + clamp + 33x33 matvec + add_time -> h[b,w,33] -------
__global__ void k_head(const float* __restrict__ zz, const float* __restrict__ lc1,
                       float* __restrict__ h) {
    __shared__ float lw[33 * 33];
    for (int j = threadIdx.x; j < 1089; j += 256) lw[j] = lc1[j];
    __syncthreads();
    int idx = blockIdx.x * 256 + threadIdx.x;
    if (idx >= BB * W3) return;
    const float* zp = zz + (size_t)idx * C2;
    float x[32];
    float ssq = 0.f;
#pragma unroll
    for (int i = 0; i < 32; i++) {
        x[i] = zp[i];
        ssq += x[i] * x[i];
    }
    float inv = 1.f / (sqrtf(ssq) + 1e-8f);
    float s2 = 0.f;
#pragma unroll
    for (int i = 0; i < 32; i++) {
        x[i] *= inv;
        s2 += x[i] * x[i];
    }
    float t = sqrtf(1.f + s2);
    float pre0 = fmaxf(t, 1.f);
    float* hp = h + (size_t)idx * CH;
    float sy = 0.f;
    for (int o = 1; o < 33; o++) {
        const float* wr = lw + o * 33;
        float a = wr[0] * pre0;
#pragma unroll
        for (int i = 0; i < 32; i++) a = fmaf(wr[1 + i], x[i], a);
        hp[o] = a;
        sy += a * a;
    }
    hp[0] = sqrtf(1.f + sy);
}

// ------- fused lorentz_bn + elu + add_time, one block per w, butterfly reduce -------
__global__ void k_lbn(const float* __restrict__ h, const float* __restrict__ bs,
                      float* __restrict__ g) {
    int w = blockIdx.x;
    int b = threadIdx.x;  // 128
    __shared__ float wsum[2][33];
    __shared__ float vred[2];
    float x[33];
    const float* hp = h + ((size_t)b * W3 + w) * CH;
#pragma unroll
    for (int ch = 0; ch < 33; ch++) x[ch] = hp[ch];
    float mu[33];
#pragma unroll
    for (int ch = 0; ch < 33; ch++) {
        float s = x[ch];
        s += __shfl_xor(s, 1);  s += __shfl_xor(s, 2);  s += __shfl_xor(s, 4);
        s += __shfl_xor(s, 8);  s += __shfl_xor(s, 16); s += __shfl_xor(s, 32);
        mu[ch] = s;
    }
    int wave = b >> 6;
    if ((b & 63) == 0) {
#pragma unroll
        for (int ch = 0; ch < 33; ch++) wsum[wave][ch] = mu[ch];
    }
    __syncthreads();
#pragma unroll
    for (int ch = 0; ch < 33; ch++) mu[ch] = (wsum[0][ch] + wsum[1][ch]) * (1.f / 128.f);
    float a0 = mu[0], sp = 0.f;
#pragma unroll
    for (int i = 1; i < 33; i++) sp = fmaf(mu[i], mu[i], sp);
    float rd = rsqrtf(fmaxf(a0 * a0 - sp, 1e-8f));
#pragma unroll
    for (int ch = 0; ch < 33; ch++) mu[ch] *= rd;
    float xin = x[0] * mu[0];
#pragma unroll
    for (int i = 1; i < 33; i++) xin -= x[i] * mu[i];
    float dist = acoshf(fmaxf(xin, 1.f + 1e-7f));
    float dq = dist * dist;
    dq += __shfl_xor(dq, 1);  dq += __shfl_xor(dq, 2);  dq += __shfl_xor(dq, 4);
    dq += __shfl_xor(dq, 8);  dq += __shfl_xor(dq, 16); dq += __shfl_xor(dq, 32);
    if ((b & 63) == 0) vred[wave] = dq;
    __syncthreads();
    float var = (vred[0] + vred[1]) * (1.f / 128.f);
    // u = x - xin*mu (reuse x)
#pragma unroll
    for (int ch = 0; ch < 33; ch++) x[ch] = x[ch] - xin * mu[ch];
    float lu = -x[0] * x[0];
#pragma unroll
    for (int i = 1; i < 33; i++) lu = fmaf(x[i], x[i], lu);
    float f = dist * rsqrtf(fmaxf(lu, 1e-8f));
#pragma unroll
    for (int ch = 0; ch < 33; ch++) x[ch] *= f;       // x now = v
    float corr = -x[0] / (1.f + mu[0]);
    x[0] += corr * (mu[0] + 1.f);
#pragma unroll
    for (int i = 1; i < 33; i++) x[i] = fmaf(corr, mu[i], x[i]);
    float scb = bs[w] * rsqrtf(var + 1e-5f);
#pragma unroll
    for (int ch = 0; ch < 33; ch++) x[ch] *= scb;
    float nn = -x[0] * x[0];
#pragma unroll
    for (int i = 1; i < 33; i++) nn = fmaf(x[i], x[i], nn);
    float n = sqrtf(fmaxf(nn, 1e-9f));
    float shn = sinhf(n) / n;
    float sg = 0.f;
    float* gp = g + ((size_t)b * W3 + w) * CH;
#pragma unroll
    for (int i = 1; i < 33; i++) {
        float e = shn * x[i];
        e = (e > 0.f) ? e : expm1f(e);
        gp[i] = e;
        sg = fmaf(e, e, sg);
    }
    gp[0] = sqrtf(1.f + sg);
}

// ------- lorentz avgpool + flatten -> feats into d_out (+tnew side buffer) -------
__global__ void k_lpool(const float* __restrict__ g, float* __restrict__ out,
                        float* __restrict__ tnew) {
    int b = blockIdx.x;
    int wp = threadIdx.x;  // 128
    __shared__ float red[128];
    const float* gp = g + ((size_t)b * W3 + wp * 4) * CH;
    float avg[33];
#pragma unroll
    for (int ch = 0; ch < 33; ch++) avg[ch] = 0.f;
    for (int j = 0; j < 4; j++) {
#pragma unroll
        for (int ch = 0; ch < 33; ch++) avg[ch] += gp[j * CH + ch];
    }
#pragma unroll
    for (int ch = 0; ch < 33; ch++) avg[ch] *= 0.25f;
    float sp = 0.f;
#pragma unroll
    for (int i = 1; i < 33; i++) sp = fmaf(avg[i], avg[i], sp);
    float l = avg[0] * avg[0] - sp;
    float rd = rsqrtf(fmaxf(l, 1e-8f));
    float q0 = avg[0] * rd;
    float* fb = out + 512 + (size_t)b * 4097;
#pragma unroll
    for (int i = 1; i < 33; i++) fb[1 + wp * 32 + (i - 1)] = avg[i] * rd;
    red[wp] = q0 * q0;
    __syncthreads();
    for (int s = 64; s > 0; s >>= 1) {
        if (wp < s) red[wp] += red[wp + s];
        __syncthreads();
    }
    if (wp == 0) {
        float tn = sqrtf(fmaxf(red[0] - 127.f, 1e-8f));
        fb[0] = tn;
        tnew[b] = tn;
    }
}

__global__ void k_mlrprep(const float* __restrict__ z, const float* __restrict__ a,
                          float* __restrict__ prep) {
    __shared__ float red[256];
    for (int c = 0; c < 4; c++) {
        float s = 0.f;
        for (int j = threadIdx.x; j < FEAT; j += 256) {
            float v = z[c * FEAT + j];
            s = fmaf(v, v, s);
        }
        red[threadIdx.x] = s;
        __syncthreads();
        for (int st = 128; st > 0; st >>= 1) {
            if (threadIdx.x < st) red[threadIdx.x] += red[threadIdx.x + st];
            __syncthreads();
        }
        if (threadIdx.x == 0) {
            float nz = sqrtf(red[0]);
            float ca = coshf(a[c]), sa = sinhf(a[c]);
            float wt = sa * nz;
            float cb = ca * nz;
            float bb = sqrtf(fmaxf(cb * cb - wt * wt, 1e-8f));
            prep[c] = wt;
            prep[4 + c] = bb;
            prep[8 + c] = ca;
        }
        __syncthreads();
    }
}

__global__ void k_mlr(const float* __restrict__ out_feats, const float* __restrict__ tnew,
                      const float* __restrict__ z, const float* __restrict__ prep,
                      float* __restrict__ logits) {
    int b = blockIdx.x;
    __shared__ float red[256];
    const float* fs = out_feats + (size_t)b * 4097 + 1;
    for (int c = 0; c < 4; c++) {
        float s = 0.f;
        for (int j = threadIdx.x; j < FEAT; j += 256) s = fmaf(fs[j], z[c * FEAT + j], s);
        red[threadIdx.x] = s;
        __syncthreads();
        for (int st = 128; st > 0; st >>= 1) {
            if (threadIdx.x < st) red[threadIdx.x] += red[threadIdx.x + st];
            __syncthreads();
        }
        if (threadIdx.x == 0) {
            float alpha = -tnew[b] * prep[c] + prep[8 + c] * red[0];
            float bb = prep[4 + c];
            float d = fabsf(asinhf(alpha / bb));
            float sg = (alpha > 0.f) ? 1.f : ((alpha < 0.f) ? -1.f : 0.f);
            logits[b * 4 + c] = sg * bb * d;
        }
        __syncthreads();
    }
}

extern "C" void kernel_launch(void* const* d_in, const int* in_sizes, int n_in,
                              void* d_out, int out_size, void* d_ws, size_t ws_size,
                              hipStream_t stream) {
    const float* in   = (const float*)d_in[0];
    const float* w1   = (const float*)d_in[2];   // conv1_w (16,1,1,32)
    const float* g1   = (const float*)d_in[3];   // bn1_gamma (only sign matters)
    const float* w2   = (const float*)d_in[5];   // conv2_w (32,1,64,1)
    const float* g2   = (const float*)d_in[6];
    const float* b2   = (const float*)d_in[7];
    const float* ew   = (const float*)d_in[8];   // ec1_w (32,1,1,16)
    const float* lc1  = (const float*)d_in[9];   // (33,33)
    const float* bs   = (const float*)d_in[10];  // bn_s (513)
    const float* mlra = (const float*)d_in[11];  // (4,)
    const float* mlrz = (const float*)d_in[12];  // (4,4096)
    float* out = (float*)d_out;
    float* ws = (float*)d_ws;

    float* P    = ws + OFF_P;
    float* PSUM = ws + OFF_PSUM;
    float* PSQ  = ws + OFF_PSQ;
    float* SS   = ws + OFF_SS;
    float* Y    = ws + OFF_Y;
    float* ZZ   = ws + OFF_ZZ;
    float* H    = ws + OFF_H;
    float* G    = ws + OFF_G;
    float* TN   = ws + OFF_TNEW;
    float* PREP = ws + OFF_PREP;

    k_p<<<dim3(16, 128), 128, 0, stream>>>(in, w2, P);
    k_stats<<<dim3(32, 128), 256, 0, stream>>>(P, w1, g1, PSUM, PSQ);
    k_bn2fin<<<1, 64, 0, stream>>>(PSUM, PSQ, g2, b2, SS);
    k_cpool<<<dim3(32, 128), 256, 0, stream>>>(P, w1, g1, SS, Y);
    k_ec1<<<dim3(65, 128), 256, 0, stream>>>(Y, ew, ZZ);
    k_head<<<257, 256, 0, stream>>>(ZZ, lc1, H);
    k_lbn<<<513, 128, 0, stream>>>(H, bs, G);
    k_lpool<<<128, 128, 0, stream>>>(G, out, TN);
    k_mlrprep<<<1, 256, 0, stream>>>(mlrz, mlra, PREP);
    k_mlr<<<128, 256, 0, stream>>>(out + 512, TN, mlrz, PREP, out);
}